// Round 1
// baseline (844.065 us; speedup 1.0000x reference)
//
#include <hip/hip_runtime.h>
#include <hip/hip_bf16.h>

#define TOK 8192
#define OUTD 768
#define KD 32768

#define BM 256
#define BN 256
#define BK 64
#define SPLITK 8
#define KCHUNK (KD / SPLITK)   // 4096
#define NKT (KCHUNK / BK)      // 64
#define THREADS 512

typedef __attribute__((ext_vector_type(4))) float f32x4;
typedef __attribute__((ext_vector_type(8))) short bf16x8;
typedef __attribute__((ext_vector_type(4))) unsigned int u32x4;

__device__ __forceinline__ unsigned pack2(float lo, float hi) {
    __hip_bfloat162 h = __float22bfloat162_rn(make_float2(lo, hi));
    unsigned u;
    __builtin_memcpy(&u, &h, 4);
    return u;
}

__device__ __forceinline__ u32x4 cvt_chunk(f32x4 a, f32x4 b) {
    u32x4 r;
    r[0] = pack2(a[0], a[1]);
    r[1] = pack2(a[2], a[3]);
    r[2] = pack2(b[0], b[1]);
    r[3] = pack2(b[2], b[3]);
    return r;
}

// ---------------------------------------------------------------------------
// Kernel 0: negc[o] = -dot(W[o,:], b_pre)   (rank-1 bias correction)
// ---------------------------------------------------------------------------
__global__ void colbias_kernel(const float* __restrict__ W,
                               const float* __restrict__ bp,
                               float* __restrict__ negc) {
    int o = blockIdx.x;
    int tid = threadIdx.x;  // 256
    const float* wr = W + (long)o * KD;
    float s = 0.f;
    for (int i = tid * 4; i < KD; i += 256 * 4) {
        f32x4 w = *(const f32x4*)(wr + i);
        f32x4 b = *(const f32x4*)(bp + i);
        s += w[0] * b[0] + w[1] * b[1] + w[2] * b[2] + w[3] * b[3];
    }
    #pragma unroll
    for (int off = 32; off > 0; off >>= 1) s += __shfl_down(s, off);
    __shared__ float red[4];
    if ((tid & 63) == 0) red[tid >> 6] = s;
    __syncthreads();
    if (tid == 0) negc[o] = -(red[0] + red[1] + red[2] + red[3]);
}

// ---------------------------------------------------------------------------
// Kernel 1: out[n][o] = negc[o]   (init; also replaces memset for atomics)
// ---------------------------------------------------------------------------
__global__ void init_kernel(const float* __restrict__ negc,
                            float* __restrict__ out) {
    long idx = ((long)blockIdx.x * blockDim.x + threadIdx.x) * 4;
    int col = (int)(idx % OUTD);
    f32x4 v = *(const f32x4*)(negc + col);
    *(f32x4*)(out + idx) = v;
}

// ---------------------------------------------------------------------------
// Kernel 2: split-K bf16 MFMA GEMM, atomicAdd epilogue.
//   out[m][n] += sum_k bf16(x[m][k]) * bf16(W[n][k])
// ---------------------------------------------------------------------------
__global__ __launch_bounds__(THREADS) void decoder_gemm(
    const float* __restrict__ X, const float* __restrict__ W,
    float* __restrict__ Out) {
    // LDS: As 256x64 bf16 (32KB) + Bs 256x64 bf16 (32KB), row stride 128B,
    // XOR-swizzled: byte ^= (row&7)<<4 within each 128B row.
    __shared__ char lds[BM * BK * 2 + BN * BK * 2];
    char* As = lds;
    char* Bs = lds + BM * BK * 2;

    int bid = blockIdx.x;
    int ks = bid & (SPLITK - 1);
    int t = bid >> 3;
    int nt = t % 3;
    int mt = t / 3;
    const int row0 = mt * BM;
    const int col0 = nt * BN;
    const long k0 = (long)ks * KCHUNK;

    const int tid = threadIdx.x;
    const int lane = tid & 63;
    const int wid = tid >> 6;
    const int wm = wid >> 2;  // 0..1 -> 128-row half
    const int wn = wid & 3;   // 0..3 -> 64-col quarter

    const float* Xb = X + (long)row0 * KD + k0;
    const float* Wb = W + (long)col0 * KD + k0;

    // staging registers: 4 chunks of 8 k-elements for each of x and W
    f32x4 xr[4][2], wr[4][2];

    auto LOAD = [&](int kt) {
        long kb = (long)kt * BK;
        #pragma unroll
        for (int i = 0; i < 4; ++i) {
            int c = tid + i * THREADS;     // 0..2047
            int r = c >> 3;                // tile row 0..255
            int kc = c & 7;                // k-octet 0..7
            const f32x4* px = (const f32x4*)(Xb + (long)r * KD + kb + kc * 8);
            xr[i][0] = px[0];
            xr[i][1] = px[1];
            const f32x4* pw = (const f32x4*)(Wb + (long)r * KD + kb + kc * 8);
            wr[i][0] = pw[0];
            wr[i][1] = pw[1];
        }
    };

    auto STORE = [&]() {
        #pragma unroll
        for (int i = 0; i < 4; ++i) {
            int c = tid + i * THREADS;
            int r = c >> 3;
            int kc = c & 7;
            int off = r * 128 + ((kc * 16) ^ ((r & 7) << 4));
            *(u32x4*)(As + off) = cvt_chunk(xr[i][0], xr[i][1]);
            *(u32x4*)(Bs + off) = cvt_chunk(wr[i][0], wr[i][1]);
        }
    };

    f32x4 acc[8][4];
    #pragma unroll
    for (int m = 0; m < 8; ++m)
        #pragma unroll
        for (int n = 0; n < 4; ++n) acc[m][n] = (f32x4){0.f, 0.f, 0.f, 0.f};

    LOAD(0);
    for (int kt = 0; kt < NKT; ++kt) {
        __syncthreads();   // previous compute done reading LDS
        STORE();
        __syncthreads();   // tile visible
        if (kt + 1 < NKT) LOAD(kt + 1);  // prefetch under MFMA

        #pragma unroll
        for (int kk = 0; kk < 2; ++kk) {
            int kbase = kk * 64 + ((lane >> 4) << 4);  // byte offset of 8-k frag
            bf16x8 bfr[4];
            #pragma unroll
            for (int n = 0; n < 4; ++n) {
                int r = wn * 64 + n * 16 + (lane & 15);
                bfr[n] = *(const bf16x8*)(Bs + r * 128 + (kbase ^ ((r & 7) << 4)));
            }
            #pragma unroll
            for (int m = 0; m < 8; ++m) {
                int r = wm * 128 + m * 16 + (lane & 15);
                bf16x8 afr = *(const bf16x8*)(As + r * 128 + (kbase ^ ((r & 7) << 4)));
                #pragma unroll
                for (int n = 0; n < 4; ++n)
                    acc[m][n] = __builtin_amdgcn_mfma_f32_16x16x32_bf16(
                        afr, bfr[n], acc[m][n], 0, 0, 0);
            }
        }
    }

    // epilogue: atomic accumulate split-K partials
    // C/D layout (m89-verified): col = lane&15, row = (lane>>4)*4 + reg
    #pragma unroll
    for (int m = 0; m < 8; ++m) {
        int row = row0 + wm * 128 + m * 16 + ((lane >> 4) << 2);
        #pragma unroll
        for (int n = 0; n < 4; ++n) {
            int col = col0 + wn * 64 + n * 16 + (lane & 15);
            #pragma unroll
            for (int i = 0; i < 4; ++i)
                atomicAdd(&Out[(long)(row + i) * OUTD + col], acc[m][n][i]);
        }
    }
}

// ---------------------------------------------------------------------------
extern "C" void kernel_launch(void* const* d_in, const int* in_sizes, int n_in,
                              void* d_out, int out_size, void* d_ws,
                              size_t ws_size, hipStream_t stream) {
    const float* x = (const float*)d_in[0];
    const float* W = (const float*)d_in[1];
    const float* bp = (const float*)d_in[2];
    float* out = (float*)d_out;
    float* negc = (float*)d_ws;  // 768 floats of scratch

    hipLaunchKernelGGL(colbias_kernel, dim3(OUTD), dim3(256), 0, stream, W, bp,
                       negc);
    hipLaunchKernelGGL(init_kernel, dim3((TOK * OUTD) / (256 * 4)), dim3(256),
                       0, stream, negc, out);
    hipLaunchKernelGGL(decoder_gemm,
                       dim3((TOK / BM) * (OUTD / BN) * SPLITK), dim3(THREADS),
                       0, stream, x, W, out);
}

// Round 2
// 740.979 us; speedup vs baseline: 1.1391x; 1.1391x over previous
//
#include <hip/hip_runtime.h>
#include <hip/hip_bf16.h>

#define TOK 8192
#define OUTD 768
#define KD 32768

#define BM 256
#define BN 256
#define BK 64
#define SPLITK 8
#define KCHUNK (KD / SPLITK)   // 4096
#define NKT (KCHUNK / BK)      // 64
#define THREADS 512

typedef __attribute__((ext_vector_type(4))) float f32x4;
typedef __attribute__((ext_vector_type(16))) float f32x16;
typedef __attribute__((ext_vector_type(8))) short bf16x8;
typedef __attribute__((ext_vector_type(4))) unsigned int u32x4;

__device__ __forceinline__ unsigned pack2(float lo, float hi) {
    __hip_bfloat162 h = __float22bfloat162_rn(make_float2(lo, hi));
    unsigned u;
    __builtin_memcpy(&u, &h, 4);
    return u;
}

__device__ __forceinline__ u32x4 cvt_chunk(f32x4 a, f32x4 b) {
    u32x4 r;
    r[0] = pack2(a[0], a[1]);
    r[1] = pack2(a[2], a[3]);
    r[2] = pack2(b[0], b[1]);
    r[3] = pack2(b[2], b[3]);
    return r;
}

// ---------------------------------------------------------------------------
// Kernel 0: negc[o] = -dot(W[o,:], b_pre)   (rank-1 bias correction)
// ---------------------------------------------------------------------------
__global__ void colbias_kernel(const float* __restrict__ W,
                               const float* __restrict__ bp,
                               float* __restrict__ negc) {
    int o = blockIdx.x;
    int tid = threadIdx.x;  // 256
    const float* wr = W + (long)o * KD;
    float s = 0.f;
    for (int i = tid * 4; i < KD; i += 256 * 4) {
        f32x4 w = *(const f32x4*)(wr + i);
        f32x4 b = *(const f32x4*)(bp + i);
        s += w[0] * b[0] + w[1] * b[1] + w[2] * b[2] + w[3] * b[3];
    }
    #pragma unroll
    for (int off = 32; off > 0; off >>= 1) s += __shfl_down(s, off);
    __shared__ float red[4];
    if ((tid & 63) == 0) red[tid >> 6] = s;
    __syncthreads();
    if (tid == 0) negc[o] = -(red[0] + red[1] + red[2] + red[3]);
}

// ---------------------------------------------------------------------------
// Kernel 1: out[n][o] = negc[o]   (init; also zero-base for split-K atomics)
// ---------------------------------------------------------------------------
__global__ void init_kernel(const float* __restrict__ negc,
                            float* __restrict__ out) {
    long idx = ((long)blockIdx.x * blockDim.x + threadIdx.x) * 4;
    int col = (int)(idx % OUTD);
    f32x4 v = *(const f32x4*)(negc + col);
    *(f32x4*)(out + idx) = v;
}

// ---------------------------------------------------------------------------
// Kernel 2: split-K bf16 MFMA GEMM (32x32x16), double-buffered LDS,
// one barrier per K-step, reg-staged f32->bf16 cvt, atomicAdd epilogue.
// ---------------------------------------------------------------------------
__global__ __launch_bounds__(THREADS, 2) void decoder_gemm(
    const float* __restrict__ X, const float* __restrict__ W,
    float* __restrict__ Out) {
    // 2 buffers x (A 256x64 bf16 = 32KB, B 256x64 bf16 = 32KB) = 128 KiB.
    // Rows stride 128B, XOR-swizzled: byte ^= (row&7)<<4.
    __shared__ char lds[2 * 65536];

    int bid = blockIdx.x;
    int ks = bid & (SPLITK - 1);
    int t = bid >> 3;
    int nt = t % 3;
    int mt = t / 3;
    const int row0 = mt * BM;
    const int col0 = nt * BN;
    const long k0 = (long)ks * KCHUNK;

    const int tid = threadIdx.x;
    const int lane = tid & 63;
    const int wid = tid >> 6;
    const int wm = wid >> 2;   // 0..1 -> 128-row half of A-tile
    const int wn = wid & 3;    // 0..3 -> 64-col quarter of B-tile
    const int l31 = lane & 31;
    const int hi = lane >> 5;  // selects k-octet within 16-k fragment

    const float* Xb = X + (long)row0 * KD + k0;
    const float* Wb = W + (long)col0 * KD + k0;

    // staging: per thread, rows r0 + i*64, k-octet kc (8 f32 = 2 f32x4)
    const int r0 = tid >> 3;   // 0..63
    const int kc = tid & 7;    // constant across i (i*512 % 8 == 0)
    f32x4 xr[4][2], wr[4][2];

    auto LOAD = [&](int kt) {
        long kb = (long)kt * BK + kc * 8;
        #pragma unroll
        for (int i = 0; i < 4; ++i) {
            const f32x4* px = (const f32x4*)(Xb + (long)(r0 + i * 64) * KD + kb);
            xr[i][0] = px[0];
            xr[i][1] = px[1];
            const f32x4* pw = (const f32x4*)(Wb + (long)(r0 + i * 64) * KD + kb);
            wr[i][0] = pw[0];
            wr[i][1] = pw[1];
        }
    };

    // swizzled store offset base; (r0+i*64)&7 == r0&7
    const int soffBase = r0 * 128 + ((kc * 16) ^ ((r0 & 7) << 4));

    auto STORE = [&](int buf) {
        char* As = lds + buf * 65536;
        char* Bs = As + 32768;
        #pragma unroll
        for (int i = 0; i < 4; ++i) {
            int off = soffBase + i * 64 * 128;
            *(u32x4*)(As + off) = cvt_chunk(xr[i][0], xr[i][1]);
            *(u32x4*)(Bs + off) = cvt_chunk(wr[i][0], wr[i][1]);
        }
    };

    // fragment read offsets: row*128 + ((kk*32 + hi*16) ^ ((row&7)<<4))
    //  = (row*128 + ((hi*16) ^ ((row&7)<<4))) ^ (kk*32)    [bit-disjoint]
    int aoff[4], boff[2];
    #pragma unroll
    for (int m = 0; m < 4; ++m) {
        int row = wm * 128 + m * 32 + l31;
        aoff[m] = row * 128 + ((hi * 16) ^ ((row & 7) << 4));
    }
    #pragma unroll
    for (int n = 0; n < 2; ++n) {
        int row = wn * 64 + n * 32 + l31;
        boff[n] = row * 128 + ((hi * 16) ^ ((row & 7) << 4));
    }

    f32x16 acc[4][2];
    #pragma unroll
    for (int m = 0; m < 4; ++m)
        #pragma unroll
        for (int n = 0; n < 2; ++n)
            #pragma unroll
            for (int r = 0; r < 16; ++r) acc[m][n][r] = 0.f;

    LOAD(0);
    STORE(0);
    __syncthreads();

    for (int kt = 0; kt < NKT; ++kt) {
        const int cur = kt & 1;
        const bool more = (kt + 1 < NKT);
        if (more) LOAD(kt + 1);  // global loads in flight under compute

        const char* As = lds + cur * 65536;
        const char* Bs = As + 32768;
        #pragma unroll
        for (int kk = 0; kk < 4; ++kk) {
            bf16x8 bfr[2], afr[4];
            #pragma unroll
            for (int n = 0; n < 2; ++n)
                bfr[n] = *(const bf16x8*)(Bs + (boff[n] ^ (kk * 32)));
            #pragma unroll
            for (int m = 0; m < 4; ++m)
                afr[m] = *(const bf16x8*)(As + (aoff[m] ^ (kk * 32)));
            __builtin_amdgcn_s_setprio(1);
            #pragma unroll
            for (int m = 0; m < 4; ++m)
                #pragma unroll
                for (int n = 0; n < 2; ++n)
                    acc[m][n] = __builtin_amdgcn_mfma_f32_32x32x16_bf16(
                        afr[m], bfr[n], acc[m][n], 0, 0, 0);
            __builtin_amdgcn_s_setprio(0);
        }

        if (more) STORE(cur ^ 1);  // cvt waits (counted) on its own loads only
        __syncthreads();           // writes visible; readers of buf[cur] done
    }

    // epilogue: atomic accumulate split-K partials
    // 32x32 C/D layout (m74/m101): col = lane&31, row = (r&3)+8*(r>>2)+4*(lane>>5)
    #pragma unroll
    for (int m = 0; m < 4; ++m) {
        int rowb = row0 + wm * 128 + m * 32 + 4 * hi;
        #pragma unroll
        for (int n = 0; n < 2; ++n) {
            int col = col0 + wn * 64 + n * 32 + l31;
            #pragma unroll
            for (int r = 0; r < 16; ++r) {
                int row = rowb + (r & 3) + 8 * (r >> 2);
                atomicAdd(&Out[(long)row * OUTD + col], acc[m][n][r]);
            }
        }
    }
}

// ---------------------------------------------------------------------------
extern "C" void kernel_launch(void* const* d_in, const int* in_sizes, int n_in,
                              void* d_out, int out_size, void* d_ws,
                              size_t ws_size, hipStream_t stream) {
    const float* x = (const float*)d_in[0];
    const float* W = (const float*)d_in[1];
    const float* bp = (const float*)d_in[2];
    float* out = (float*)d_out;
    float* negc = (float*)d_ws;  // 768 floats of scratch

    hipLaunchKernelGGL(colbias_kernel, dim3(OUTD), dim3(256), 0, stream, W, bp,
                       negc);
    hipLaunchKernelGGL(init_kernel, dim3((TOK * OUTD) / (256 * 4)), dim3(256),
                       0, stream, negc, out);
    hipLaunchKernelGGL(decoder_gemm,
                       dim3((TOK / BM) * (OUTD / BN) * SPLITK), dim3(THREADS),
                       0, stream, x, W, out);
}